// Round 3
// baseline (1241.289 us; speedup 1.0000x reference)
//
#include <hip/hip_runtime.h>

#define D 128
#define DE 16
#define NL 4
#define K1P 288   // 2D+DE=272 padded to 9*32
#define KU 256    // 2D
#define EPSV 1e-5f

using f32x4  = __attribute__((ext_vector_type(4))) float;
using bf16x8 = __attribute__((ext_vector_type(8))) short;

#define MFMA16(a, b, c) __builtin_amdgcn_mfma_f32_16x16x32_bf16((a), (b), (c), 0, 0, 0)

__device__ __forceinline__ unsigned short f2bf(float x) {
  unsigned int u = __float_as_uint(x);
  u = (u + 0x7FFFu + ((u >> 16) & 1u)) >> 16;  // RNE
  return (unsigned short)u;
}

__device__ __forceinline__ void gload_lds16(const void* gp, void* lp) {
  typedef __attribute__((address_space(1))) unsigned int as1_u32;
  typedef __attribute__((address_space(3))) unsigned int as3_u32;
  __builtin_amdgcn_global_load_lds((as1_u32*)(unsigned long long)gp,
                                   (as3_u32*)(unsigned int)(unsigned long long)lp,
                                   16, 0, 0);
}

__device__ __forceinline__ bf16x8 pack8(float4 a, float4 b) {
  bf16x8 o;
  o[0] = (short)f2bf(a.x); o[1] = (short)f2bf(a.y);
  o[2] = (short)f2bf(a.z); o[3] = (short)f2bf(a.w);
  o[4] = (short)f2bf(b.x); o[5] = (short)f2bf(b.y);
  o[6] = (short)f2bf(b.z); o[7] = (short)f2bf(b.w);
  return o;
}

// ---------------- prep kernels ----------------

// out[l][c][Kpad] = W[l][k][c] * g[l][c] * rsqrt(v[l][c]+eps), zero-padded k>=K
__global__ void wprep_kernel(const float* __restrict__ W, const float* __restrict__ g,
                             const float* __restrict__ v, unsigned short* __restrict__ out,
                             int K, int Kpad, int total) {
  int idx = blockIdx.x * 256 + threadIdx.x;
  if (idx >= total) return;
  int k = idx % Kpad;
  int c = (idx / Kpad) & (D - 1);
  int l = idx / (Kpad * D);
  float val = 0.f;
  if (k < K) {
    float s = g[l * D + c] * rsqrtf(v[l * D + c] + EPSV);
    val = W[((size_t)(l * K + k)) * D + c] * s;
  }
  out[idx] = f2bf(val);
}

__global__ void bprep_kernel(const float* __restrict__ b, const float* __restrict__ g,
                             const float* __restrict__ be, const float* __restrict__ m,
                             const float* __restrict__ v, float* __restrict__ out) {
  int idx = blockIdx.x * 256 + threadIdx.x;
  if (idx >= NL * D) return;
  float s = g[idx] * rsqrtf(v[idx] + EPSV);
  out[idx] = (b[idx] - m[idx]) * s + be[idx];
}

__global__ void cvt4_kernel(const float* __restrict__ src, unsigned short* __restrict__ dst, int n4) {
  int idx = blockIdx.x * 256 + threadIdx.x;
  if (idx >= n4) return;
  float4 f = reinterpret_cast<const float4*>(src)[idx];
  unsigned long long p = (unsigned long long)f2bf(f.x)
                       | ((unsigned long long)f2bf(f.y) << 16)
                       | ((unsigned long long)f2bf(f.z) << 32)
                       | ((unsigned long long)f2bf(f.w) << 48);
  reinterpret_cast<unsigned long long*>(dst)[idx] = p;
}

// h = x @ Win + b_in  (f32), also write bf16 copy
__global__ void xproj_kernel(const float* __restrict__ x, const float* __restrict__ Win,
                             const float* __restrict__ bin, float* __restrict__ h,
                             unsigned short* __restrict__ hbf, int N) {
  int t = blockIdx.x * 256 + threadIdx.x;
  int node = t >> 7, c = t & 127;
  if (node >= N) return;
  const float* xr = x + (size_t)node * 64;
  float acc = bin[c];
#pragma unroll
  for (int k = 0; k < 64; ++k) acc = fmaf(xr[k], Win[k * D + c], acc);
  h[t] = acc;
  hbf[t] = f2bf(acc);
}

// ---------------- edge message kernel ----------------
// per block: 128 edges, 4 waves, wave does M=32 x N=128.
// GEMM1: concat(h[dst],h[src],eattr) [K=272->288] @ W1t ; relu -> m1 (LDS)
// GEMM2: m1 @ W2t ; relu -> atomicAdd into agg[dst]
__global__ __launch_bounds__(256)
void edge_kernel(const unsigned short* __restrict__ hbf,
                 const unsigned short* __restrict__ ebf,
                 const int* __restrict__ eidx,
                 const unsigned short* __restrict__ W1t,   // [D][K1P]
                 const unsigned short* __restrict__ W2t,   // [D][D]
                 const float* __restrict__ b1,
                 const float* __restrict__ b2,
                 float* __restrict__ agg, int E) {
  __shared__ unsigned short Bls[4096];        // 8 KB B-tile [g][c][8]
  __shared__ unsigned short m1ls[128 * 128];  // 32 KB, XOR-swizzled rows
  __shared__ int dstls[128];

  const int tid = threadIdx.x;
  const int wid = tid >> 6;
  const int lane = tid & 63;
  const int g = lane >> 4;
  const int r = lane & 15;
  const int ebase = blockIdx.x * 128;

  if (tid < 128) {
    int e = ebase + tid;
    dstls[tid] = (e < E) ? eidx[E + e] : 0;
  }

  const int er0 = ebase + wid * 32 + r;
  const int er1 = er0 + 16;
  const bool ev0 = er0 < E, ev1 = er1 < E;
  const int dst0 = ev0 ? eidx[E + er0] : 0;
  const int src0 = ev0 ? eidx[er0] : 0;
  const int dst1 = ev1 ? eidx[E + er1] : 0;
  const int src1 = ev1 ? eidx[er1] : 0;

  float bia1[8], bia2[8];
#pragma unroll
  for (int n = 0; n < 8; ++n) { bia1[n] = b1[n * 16 + r]; bia2[n] = b2[n * 16 + r]; }

  f32x4 acc0[8], acc1[8];
#pragma unroll
  for (int n = 0; n < 8; ++n)
#pragma unroll
    for (int q = 0; q < 4; ++q) { acc0[n][q] = 0.f; acc1[n][q] = 0.f; }

  bf16x8 az;
#pragma unroll
  for (int q = 0; q < 8; ++q) az[q] = 0;

  const int sc = tid & 127;   // staged weight row (output col)
  const int sg = tid >> 7;    // staged k-slice

  // ---- GEMM1: 9 K-steps of 32 ----
#pragma unroll
  for (int s = 0; s < 9; ++s) {
    __syncthreads();
    gload_lds16(W1t + sc * K1P + s * 32 + sg * 8,       (char*)Bls + wid * 1024);
    gload_lds16(W1t + sc * K1P + s * 32 + (2 + sg) * 8, (char*)Bls + 4096 + wid * 1024);
    __syncthreads();

    bf16x8 a0, a1;
    if (s < 4) {
      a0 = *reinterpret_cast<const bf16x8*>(hbf + (size_t)dst0 * D + s * 32 + g * 8);
      a1 = *reinterpret_cast<const bf16x8*>(hbf + (size_t)dst1 * D + s * 32 + g * 8);
    } else if (s < 8) {
      a0 = *reinterpret_cast<const bf16x8*>(hbf + (size_t)src0 * D + (s - 4) * 32 + g * 8);
      a1 = *reinterpret_cast<const bf16x8*>(hbf + (size_t)src1 * D + (s - 4) * 32 + g * 8);
    } else {
      a0 = az; a1 = az;
      if (g < 2) {
        if (ev0) a0 = *reinterpret_cast<const bf16x8*>(ebf + (size_t)er0 * DE + g * 8);
        if (ev1) a1 = *reinterpret_cast<const bf16x8*>(ebf + (size_t)er1 * DE + g * 8);
      }
    }
#pragma unroll
    for (int n = 0; n < 8; ++n) {
      bf16x8 b = *reinterpret_cast<const bf16x8*>(Bls + g * 1024 + (n * 16 + r) * 8);
      acc0[n] = MFMA16(a0, b, acc0[n]);
      acc1[n] = MFMA16(a1, b, acc1[n]);
    }
  }

  // m1 = relu(acc + bias1) -> bf16 -> swizzled LDS (C-layout: col=r, row=g*4+j)
#pragma unroll
  for (int n = 0; n < 8; ++n)
#pragma unroll
    for (int j = 0; j < 4; ++j) {
      int col = n * 16 + r;
      int row0 = wid * 32 + g * 4 + j;
      int row1 = row0 + 16;
      m1ls[row0 * 128 + (col ^ ((row0 & 7) << 3))] = f2bf(fmaxf(acc0[n][j] + bia1[n], 0.f));
      m1ls[row1 * 128 + (col ^ ((row1 & 7) << 3))] = f2bf(fmaxf(acc1[n][j] + bia1[n], 0.f));
    }

  f32x4 c0[8], c1[8];
#pragma unroll
  for (int n = 0; n < 8; ++n)
#pragma unroll
    for (int q = 0; q < 4; ++q) { c0[n][q] = 0.f; c1[n][q] = 0.f; }

  // ---- GEMM2: 4 K-steps ----
#pragma unroll
  for (int s = 0; s < 4; ++s) {
    __syncthreads();
    gload_lds16(W2t + sc * D + s * 32 + sg * 8,       (char*)Bls + wid * 1024);
    gload_lds16(W2t + sc * D + s * 32 + (2 + sg) * 8, (char*)Bls + 4096 + wid * 1024);
    __syncthreads();

    int row0 = wid * 32 + r;
    int row1 = row0 + 16;
    int k0 = s * 32 + g * 8;
    bf16x8 a0 = *reinterpret_cast<const bf16x8*>(m1ls + row0 * 128 + (k0 ^ ((row0 & 7) << 3)));
    bf16x8 a1 = *reinterpret_cast<const bf16x8*>(m1ls + row1 * 128 + (k0 ^ ((row1 & 7) << 3)));
#pragma unroll
    for (int n = 0; n < 8; ++n) {
      bf16x8 b = *reinterpret_cast<const bf16x8*>(Bls + g * 1024 + (n * 16 + r) * 8);
      c0[n] = MFMA16(a0, b, c0[n]);
      c1[n] = MFMA16(a1, b, c1[n]);
    }
  }

  // epilogue: relu(c + bias2) -> atomic scatter-add into agg[dst]
#pragma unroll
  for (int h2 = 0; h2 < 2; ++h2) {
#pragma unroll
    for (int j = 0; j < 4; ++j) {
      int rowl = wid * 32 + h2 * 16 + g * 4 + j;
      int eg = ebase + rowl;
      if (eg < E) {
        float* ap = agg + (size_t)dstls[rowl] * D + r;
#pragma unroll
        for (int n = 0; n < 8; ++n) {
          float vv = h2 ? fmaxf(c1[n][j] + bia2[n], 0.f) : fmaxf(c0[n][j] + bia2[n], 0.f);
          unsafeAtomicAdd(ap + n * 16, vv);
        }
      }
    }
  }
}

// ---------------- node update kernel ----------------
// u = relu(BN(relu(BN(concat(h,agg) @ Wu1)) @ Wu2)); h += u; hbf = bf16(h)
__global__ __launch_bounds__(256)
void node_kernel(const unsigned short* __restrict__ hbf,
                 const float* __restrict__ agg,
                 const unsigned short* __restrict__ W1t,  // [D][KU]
                 const unsigned short* __restrict__ W2t,  // [D][D]
                 const float* __restrict__ b1,
                 const float* __restrict__ b2,
                 float* __restrict__ h,
                 unsigned short* __restrict__ hbfo, int N) {
  __shared__ unsigned short Bls[4096];
  __shared__ unsigned short m1ls[128 * 128];

  const int tid = threadIdx.x;
  const int wid = tid >> 6;
  const int lane = tid & 63;
  const int g = lane >> 4;
  const int r = lane & 15;
  const int nbase = blockIdx.x * 128;

  const int nr0 = nbase + wid * 32 + r;
  const int nr1 = nr0 + 16;
  const int ar0 = (nr0 < N) ? nr0 : 0;
  const int ar1 = (nr1 < N) ? nr1 : 0;

  float bia1[8], bia2[8];
#pragma unroll
  for (int n = 0; n < 8; ++n) { bia1[n] = b1[n * 16 + r]; bia2[n] = b2[n * 16 + r]; }

  f32x4 acc0[8], acc1[8];
#pragma unroll
  for (int n = 0; n < 8; ++n)
#pragma unroll
    for (int q = 0; q < 4; ++q) { acc0[n][q] = 0.f; acc1[n][q] = 0.f; }

  const int sc = tid & 127;
  const int sg = tid >> 7;

  // ---- GEMM1: K=256, 8 steps ----
#pragma unroll
  for (int s = 0; s < 8; ++s) {
    __syncthreads();
    gload_lds16(W1t + sc * KU + s * 32 + sg * 8,       (char*)Bls + wid * 1024);
    gload_lds16(W1t + sc * KU + s * 32 + (2 + sg) * 8, (char*)Bls + 4096 + wid * 1024);
    __syncthreads();

    bf16x8 a0, a1;
    if (s < 4) {
      a0 = *reinterpret_cast<const bf16x8*>(hbf + (size_t)ar0 * D + s * 32 + g * 8);
      a1 = *reinterpret_cast<const bf16x8*>(hbf + (size_t)ar1 * D + s * 32 + g * 8);
    } else {
      const float* p0 = agg + (size_t)ar0 * D + (s - 4) * 32 + g * 8;
      const float* p1 = agg + (size_t)ar1 * D + (s - 4) * 32 + g * 8;
      a0 = pack8(*reinterpret_cast<const float4*>(p0), *reinterpret_cast<const float4*>(p0 + 4));
      a1 = pack8(*reinterpret_cast<const float4*>(p1), *reinterpret_cast<const float4*>(p1 + 4));
    }
#pragma unroll
    for (int n = 0; n < 8; ++n) {
      bf16x8 b = *reinterpret_cast<const bf16x8*>(Bls + g * 1024 + (n * 16 + r) * 8);
      acc0[n] = MFMA16(a0, b, acc0[n]);
      acc1[n] = MFMA16(a1, b, acc1[n]);
    }
  }

#pragma unroll
  for (int n = 0; n < 8; ++n)
#pragma unroll
    for (int j = 0; j < 4; ++j) {
      int col = n * 16 + r;
      int row0 = wid * 32 + g * 4 + j;
      int row1 = row0 + 16;
      m1ls[row0 * 128 + (col ^ ((row0 & 7) << 3))] = f2bf(fmaxf(acc0[n][j] + bia1[n], 0.f));
      m1ls[row1 * 128 + (col ^ ((row1 & 7) << 3))] = f2bf(fmaxf(acc1[n][j] + bia1[n], 0.f));
    }

  f32x4 c0[8], c1[8];
#pragma unroll
  for (int n = 0; n < 8; ++n)
#pragma unroll
    for (int q = 0; q < 4; ++q) { c0[n][q] = 0.f; c1[n][q] = 0.f; }

#pragma unroll
  for (int s = 0; s < 4; ++s) {
    __syncthreads();
    gload_lds16(W2t + sc * D + s * 32 + sg * 8,       (char*)Bls + wid * 1024);
    gload_lds16(W2t + sc * D + s * 32 + (2 + sg) * 8, (char*)Bls + 4096 + wid * 1024);
    __syncthreads();

    int row0 = wid * 32 + r;
    int row1 = row0 + 16;
    int k0 = s * 32 + g * 8;
    bf16x8 a0 = *reinterpret_cast<const bf16x8*>(m1ls + row0 * 128 + (k0 ^ ((row0 & 7) << 3)));
    bf16x8 a1 = *reinterpret_cast<const bf16x8*>(m1ls + row1 * 128 + (k0 ^ ((row1 & 7) << 3)));
#pragma unroll
    for (int n = 0; n < 8; ++n) {
      bf16x8 b = *reinterpret_cast<const bf16x8*>(Bls + g * 1024 + (n * 16 + r) * 8);
      c0[n] = MFMA16(a0, b, c0[n]);
      c1[n] = MFMA16(a1, b, c1[n]);
    }
  }

  // epilogue: h += relu(c + bias2); refresh bf16 h
#pragma unroll
  for (int h2 = 0; h2 < 2; ++h2) {
#pragma unroll
    for (int j = 0; j < 4; ++j) {
      int rowl = wid * 32 + h2 * 16 + g * 4 + j;
      int node = nbase + rowl;
      if (node < N) {
#pragma unroll
        for (int n = 0; n < 8; ++n) {
          int col = n * 16 + r;
          float vv = h2 ? fmaxf(c1[n][j] + bia2[n], 0.f) : fmaxf(c0[n][j] + bia2[n], 0.f);
          float hv = h[(size_t)node * D + col] + vv;
          h[(size_t)node * D + col] = hv;
          hbfo[(size_t)node * D + col] = f2bf(hv);
        }
      }
    }
  }
}

extern "C" void kernel_launch(void* const* d_in, const int* in_sizes, int n_in,
                              void* d_out, int out_size, void* d_ws, size_t ws_size,
                              hipStream_t stream) {
  const float* x     = (const float*)d_in[0];
  const int*   eidx  = (const int*)d_in[1];
  const float* eattr = (const float*)d_in[2];
  const float* Win   = (const float*)d_in[3];
  const float* bin   = (const float*)d_in[4];
  const float* Wm1 = (const float*)d_in[5];  const float* bm1 = (const float*)d_in[6];
  const float* gm1 = (const float*)d_in[7];  const float* bem1 = (const float*)d_in[8];
  const float* mm1 = (const float*)d_in[9];  const float* vm1 = (const float*)d_in[10];
  const float* Wm2 = (const float*)d_in[11]; const float* bm2 = (const float*)d_in[12];
  const float* gm2 = (const float*)d_in[13]; const float* bem2 = (const float*)d_in[14];
  const float* mm2 = (const float*)d_in[15]; const float* vm2 = (const float*)d_in[16];
  const float* Wu1 = (const float*)d_in[17]; const float* bu1 = (const float*)d_in[18];
  const float* gu1 = (const float*)d_in[19]; const float* beu1 = (const float*)d_in[20];
  const float* mu1 = (const float*)d_in[21]; const float* vu1 = (const float*)d_in[22];
  const float* Wu2 = (const float*)d_in[23]; const float* bu2 = (const float*)d_in[24];
  const float* gu2 = (const float*)d_in[25]; const float* beu2 = (const float*)d_in[26];
  const float* mu2 = (const float*)d_in[27]; const float* vu2 = (const float*)d_in[28];

  const int N = in_sizes[0] / 64;
  const int E = in_sizes[1] / 2;
  float* h = (float*)d_out;

  // workspace layout (16B-aligned slabs)
  char* ws = (char*)d_ws;
  size_t off = 0;
  float* agg = (float*)(ws + off);            off += (size_t)N * D * 4;
  unsigned short* hbf  = (unsigned short*)(ws + off); off += (size_t)N * D * 2;
  unsigned short* ebf  = (unsigned short*)(ws + off); off += (size_t)E * DE * 2;
  unsigned short* W1t  = (unsigned short*)(ws + off); off += (size_t)NL * D * K1P * 2;
  unsigned short* W2t  = (unsigned short*)(ws + off); off += (size_t)NL * D * D * 2;
  unsigned short* Wu1t = (unsigned short*)(ws + off); off += (size_t)NL * D * KU * 2;
  unsigned short* Wu2t = (unsigned short*)(ws + off); off += (size_t)NL * D * D * 2;
  float* bm1f = (float*)(ws + off); off += (size_t)NL * D * 4;
  float* bm2f = (float*)(ws + off); off += (size_t)NL * D * 4;
  float* bu1f = (float*)(ws + off); off += (size_t)NL * D * 4;
  float* bu2f = (float*)(ws + off); off += (size_t)NL * D * 4;
  if (off > ws_size) return;  // fail loudly (validation will catch poison)

  // ---- prep: fold BN into transposed bf16 weights + biases ----
  {
    int t1 = NL * D * K1P, t2 = NL * D * D, t3 = NL * D * KU;
    wprep_kernel<<<(t1 + 255) / 256, 256, 0, stream>>>(Wm1, gm1, vm1, W1t, 2 * D + DE, K1P, t1);
    wprep_kernel<<<(t2 + 255) / 256, 256, 0, stream>>>(Wm2, gm2, vm2, W2t, D, D, t2);
    wprep_kernel<<<(t3 + 255) / 256, 256, 0, stream>>>(Wu1, gu1, vu1, Wu1t, KU, KU, t3);
    wprep_kernel<<<(t2 + 255) / 256, 256, 0, stream>>>(Wu2, gu2, vu2, Wu2t, D, D, t2);
    bprep_kernel<<<2, 256, 0, stream>>>(bm1, gm1, bem1, mm1, vm1, bm1f);
    bprep_kernel<<<2, 256, 0, stream>>>(bm2, gm2, bem2, mm2, vm2, bm2f);
    bprep_kernel<<<2, 256, 0, stream>>>(bu1, gu1, beu1, mu1, vu1, bu1f);
    bprep_kernel<<<2, 256, 0, stream>>>(bu2, gu2, beu2, mu2, vu2, bu2f);
    int n4 = E * DE / 4;
    cvt4_kernel<<<(n4 + 255) / 256, 256, 0, stream>>>(eattr, ebf, n4);
  }

  // ---- input projection ----
  xproj_kernel<<<(N * D + 255) / 256, 256, 0, stream>>>(x, Win, bin, h, hbf, N);

  // ---- layers ----
  const int eblocks = (E + 127) / 128;
  const int nblocks = (N + 127) / 128;
  for (int l = 0; l < NL; ++l) {
    hipMemsetAsync(agg, 0, (size_t)N * D * 4, stream);
    edge_kernel<<<eblocks, 256, 0, stream>>>(hbf, ebf, eidx,
                                             W1t + (size_t)l * D * K1P, W2t + (size_t)l * D * D,
                                             bm1f + l * D, bm2f + l * D, agg, E);
    node_kernel<<<nblocks, 256, 0, stream>>>(hbf, agg,
                                             Wu1t + (size_t)l * D * KU, Wu2t + (size_t)l * D * D,
                                             bu1f + l * D, bu2f + l * D, h, hbf, N);
  }
}